// Round 12
// baseline (104.841 us; speedup 1.0000x reference)
//
#include <hip/hip_runtime.h>
#include <hip/hip_bf16.h>

#define N 8192
#define D_IN 256
#define HID 512
#define Z 128
#define NCAT 16
#define EPS_F 1e-16f
#define PADCAP 9472    // 64-padded perm capacity: 8192 + 16*63 = 9200 max, +slack
#define T32CAP 296     // PADCAP/32
#define T64CAP 148     // PADCAP/64
#define JY 16          // one-shot 64-j chunks per i-tile (covers n_c up to 1024)
#define NZERO 64       // blocks zeroing negpart

typedef short bf16x8 __attribute__((ext_vector_type(8)));
typedef float f32x4 __attribute__((ext_vector_type(4)));

__device__ __forceinline__ unsigned short f2bf(float f) {
    unsigned u = __float_as_uint(f);
    unsigned r = u + 0x7FFFu + ((u >> 16) & 1u);
    return (unsigned short)(r >> 16);
}
__device__ __forceinline__ float bf2f(unsigned short s) {
    return __uint_as_float(((unsigned)s) << 16);
}
__device__ __forceinline__ unsigned pack2(float a, float b) {
    return (unsigned)f2bf(a) | ((unsigned)f2bf(b) << 16);
}
__device__ __forceinline__ float softplus_f(float x) {
    return fmaxf(x, 0.f) + log1pf(expf(-fabsf(x)));
}

// async global->LDS, 16B per lane; LDS dest = wave-uniform base + lane*16
__device__ __forceinline__ void gl_lds16(const void* gptr, void* lptr) {
    __builtin_amdgcn_global_load_lds(
        (const __attribute__((address_space(1))) unsigned*)gptr,
        (__attribute__((address_space(3))) unsigned*)lptr,
        16, 0, 0);
}

struct KParams {
    const float* x; const int* c; const float* z;
    const float* W1; const float* b1; const float* W2; const float* b2;
    const float* Wz; const float* bz; const float* ws;
    float* out;
    unsigned short *Hp, *fxp, *fzp, *W1t, *W2t, *Wzt, *wsT;  // permuted+padded activations
    float *Tv, *negpart;    // Tv[PADCAP] fp32 T-dots; negpart[JY][PADCAP]
    int *perm32, *inv, *cnt, *offsP, *tcat;
};

// fp32 [R][C] 32x32 tile -> bf16 transposed [C][R]
__device__ __forceinline__ void transpose32(
    const float* in, unsigned short* out, int R, int C, int r0, int c0, char* SAc) {
    float (*tile)[33] = (float (*)[33])SAc;
    int tx = threadIdx.x & 31, ty = threadIdx.x >> 5;
#pragma unroll
    for (int q = 0; q < 4; q++)
        tile[ty + 8 * q][tx] = in[(size_t)(r0 + ty + 8 * q) * C + c0 + tx];
    __syncthreads();
#pragma unroll
    for (int q = 0; q < 4; q++)
        out[(size_t)(c0 + ty + 8 * q) * R + r0 + tx] = f2bf(tile[tx][ty + 8 * q]);
}

// ================= kernel 1: transposes | setup | negpart zero =================
__global__ __launch_bounds__(256) void k_prep(KParams P) {
    __shared__ char SA[4352];
    __shared__ int sTmp[128];
    int t = threadIdx.x, b = blockIdx.x;
    if (b < 128) {
        transpose32(P.W1, P.W1t, D_IN, HID, (b >> 4) * 32, (b & 15) * 32, SA);
    } else if (b < 192) {
        int q = b - 128;   // W2: HID x Z -> 16 r-tiles x 4 c-tiles
        transpose32(P.W2, P.W2t, HID, Z, (q >> 2) * 32, (q & 3) * 32, SA);
    } else if (b < 208) {
        int q = b - 192;
        transpose32(P.Wz, P.Wzt, Z, Z, (q >> 2) * 32, (q & 3) * 32, SA);
    } else if (b < 464) {
        int q = b - 208; int m = q >> 4; q &= 15;
        transpose32(P.ws + (size_t)m * Z * Z, P.wsT + (size_t)m * Z * Z, Z, Z,
                    (q >> 2) * 32, (q & 3) * 32, SA);
    } else if (b == 464) {
        // count / scan (64-pad) / tcat / perm32+inv fill / pad fills
        for (int i = t; i < 128; i += 256) sTmp[i] = 0;
        __syncthreads();
        for (int n = t; n < N; n += 256) atomicAdd(&sTmp[(t >> 6) * 17 + P.c[n]], 1);
        __syncthreads();
        if (t < 16) {
            int s = 0;
            for (int w = 0; w < 4; w++) s += sTmp[w * 17 + t];
            sTmp[68 + t] = s;
            P.cnt[t] = s;
        }
        __syncthreads();
        if (t == 0) {
            int sp = 0;
            for (int k = 0; k < NCAT; k++) { sTmp[84 + k] = sp; sp += ((sTmp[68 + k] + 63) >> 6) << 6; }
            sTmp[100] = sp;
        }
        __syncthreads();
        if (t < 17) P.offsP[t] = sTmp[84 + t];
        for (int q = t; q < T32CAP; q += 256) {
            int cat = -1;
            for (int k = 0; k < NCAT; k++)
                if (q * 32 >= sTmp[84 + k] && q * 32 < sTmp[84 + k + 1]) cat = k;
            P.tcat[q] = cat;
        }
        if (t < 16) {
            for (int i = sTmp[84 + t] + sTmp[68 + t]; i < sTmp[84 + t + 1]; i++) P.perm32[i] = -1;
        }
        for (int i = sTmp[100] + t; i < PADCAP; i += 256) P.perm32[i] = -1;
        __syncthreads();
        for (int n = t; n < N; n += 256) {
            int cat = P.c[n];
            int pos = atomicAdd(&sTmp[101 + cat], 1);
            int slot = sTmp[84 + cat] + pos;
            P.perm32[slot] = n;
            P.inv[n] = slot;
        }
    } else {
        // zero negpart[JY][PADCAP]
        for (int i = (b - 465) * 256 + t; i < JY * PADCAP; i += NZERO * 256)
            P.negpart[i] = 0.f;
    }
}

// MFMA GEMM tile: C = act(A @ Bt^T + bias), BM=128 BN=64 BK=64, 4 waves 2x2.
// If invp != null, output row r is written to row invp[r] (permuted scatter).
template<bool A_F32, bool RELU>
__device__ __forceinline__ void gemm_body(
    const void* __restrict__ Ap, const unsigned short* __restrict__ Btp,
    const float* __restrict__ bias, unsigned short* __restrict__ Cb,
    const int* __restrict__ invp,
    int Nn, int K, int row0, int col0, char* As, char* Bs) {
    int t = threadIdx.x;
    int wave = t >> 6, l = t & 63, l15 = l & 15, lg = l >> 4;
    int wm = (wave >> 1) * 64, wn = (wave & 1) * 32;
    f32x4 acc[4][2] = {};

    for (int kk0 = 0; kk0 < K; kk0 += 64) {
#pragma unroll
        for (int q = 0; q < 4; q++) {   // A: 128 rows x 8 chunks
            int cid = t + q * 256, row = cid >> 3, ch = cid & 7;
            uint4 w;
            if (A_F32) {
                const float* g = (const float*)Ap + (size_t)(row0 + row) * K + kk0 + ch * 8;
                float4 a0 = *(const float4*)g, a1 = *(const float4*)(g + 4);
                w.x = pack2(a0.x, a0.y); w.y = pack2(a0.z, a0.w);
                w.z = pack2(a1.x, a1.y); w.w = pack2(a1.z, a1.w);
            } else {
                w = *(const uint4*)((const unsigned short*)Ap + (size_t)(row0 + row) * K + kk0 + ch * 8);
            }
            *(uint4*)(As + row * 128 + ((ch ^ (row & 7)) << 4)) = w;
        }
#pragma unroll
        for (int q = 0; q < 2; q++) {   // B: 64 rows x 8 chunks (bf16, pre-swizzled source -> linear LDS)
            int L = t + q * 256, row = L >> 3, sc = L & 7;
            int ch = sc ^ (row & 7);
            gl_lds16(Btp + (size_t)(col0 + row) * K + kk0 + ch * 8,
                     Bs + ((q * 256 + (t >> 6) * 64) << 4));
        }
        __syncthreads();
#pragma unroll
        for (int kk = 0; kk < 2; kk++) {
            int ch = kk * 4 + lg;
            bf16x8 a[4], bq[2];
#pragma unroll
            for (int m = 0; m < 4; m++) {
                int ra = wm + m * 16 + l15;
                a[m] = *(const bf16x8*)(As + ra * 128 + ((ch ^ (ra & 7)) << 4));
            }
#pragma unroll
            for (int n2 = 0; n2 < 2; n2++) {
                int rb = wn + n2 * 16 + l15;
                bq[n2] = *(const bf16x8*)(Bs + rb * 128 + ((ch ^ (rb & 7)) << 4));
            }
#pragma unroll
            for (int m = 0; m < 4; m++)
#pragma unroll
                for (int n2 = 0; n2 < 2; n2++)
                    acc[m][n2] = __builtin_amdgcn_mfma_f32_16x16x32_bf16(a[m], bq[n2], acc[m][n2], 0, 0, 0);
        }
        __syncthreads();
    }
#pragma unroll
    for (int m = 0; m < 4; m++)
#pragma unroll
        for (int r = 0; r < 4; r++) {
            int row = row0 + wm + m * 16 + lg * 4 + r;
            int orow = invp ? invp[row] : row;
#pragma unroll
            for (int n2 = 0; n2 < 2; n2++) {
                int col = col0 + wn + n2 * 16 + l15;
                float v = acc[m][n2][r] + (bias ? bias[col] : 0.f);
                if (RELU) v = fmaxf(v, 0.f);
                Cb[(size_t)orow * Nn + col] = f2bf(v);
            }
        }
}

// Wait: gl_lds16 in gemm_body's B stage — the byte address math must match the ds_read.
// LDS linear slot L*16 holds source chunk ch = (L&7 of row slice)^... handled by caller above:
// dest linear index L = q*256 + wv*64 + lane; row=L>>3?? NO — B tile is 64 rows x 8 chunks:
// L>>3 = row, L&7 = swizzled chunk slot; source ch = (L&7)^(row&7). The per-lane source above
// uses row = L>>3 with L = t + q*256 (t==lane ordering within wave matches linear dest). OK.

// ================= kernel 2: gemm1 -> Hp (permuted) | fzp (permuted) =================
__global__ __launch_bounds__(256, 3) void k_mid(KParams P) {
    __shared__ char SA[16384];
    __shared__ char SB[8192];
    int b = blockIdx.x;
    if (b < 512) {
        gemm_body<true, true>(P.x, P.W1t, P.b1, P.Hp, P.inv, HID, D_IN,
                              (b >> 3) * 128, (b & 7) * 64, SA, SB);
    } else {
        int q = b - 512;
        gemm_body<true, false>(P.z, P.Wzt, P.bz, P.fzp, P.inv, Z, Z,
                               (q >> 1) * 128, (q & 1) * 64, SA, SB);
    }
}

// ================= kernel 3: fxp = Hp @ W2t^T + b2 (permuted streaming) =================
__global__ __launch_bounds__(256, 3) void k_fx(KParams P) {
    __shared__ char SA[16384];
    __shared__ char SB[8192];
    gemm_body<false, false>(P.Hp, P.W2t, P.b2, P.fxp, nullptr, Z, HID,
                            blockIdx.y * 128, blockIdx.x * 64, SA, SB);
}

// ================= kernel 4: fused u + neg + T-diag, one-shot 64-i x 64-j =================
__global__ __launch_bounds__(256, 3) void k_negu(KParams P) {
    __shared__ char SA[16384];     // fxp tile 64x128 bf16 swz -> then u tile
    __shared__ char SB[32768];     // wsT[cat] 128x128 bf16 swz; later first 16KB = fzp chunk
    __shared__ float negw[4][64];
    int t = threadIdx.x, it = blockIdx.y;
    int cat = P.tcat[it * 2];
    if (cat < 0) return;
    int jb = P.offsP[cat] + blockIdx.x * 64;
    if (jb >= P.offsP[cat + 1]) return;
    int jreal = P.offsP[cat] + P.cnt[cat];
    int ibase = it * 64;
    int wv = t >> 6, l15 = t & 15, lg = (t & 63) >> 4;

    // ---- stage fxp tile (16KB, 4 issues) + wsT[cat] (32KB, 8 issues) via global_load_lds ----
    const unsigned short* wsTc = P.wsT + (size_t)cat * Z * Z;
#pragma unroll
    for (int q = 0; q < 4; q++) {
        int L = q * 256 + t, row = L >> 4, ch = (L & 15) ^ (row & 7);
        gl_lds16(P.fxp + (size_t)(ibase + row) * Z + ch * 8,
                 SA + ((q * 256 + wv * 64) << 4));
    }
#pragma unroll
    for (int q = 0; q < 8; q++) {
        int L = q * 256 + t, row = L >> 4, ch = (L & 15) ^ (row & 7);
        gl_lds16(wsTc + (size_t)row * Z + ch * 8,
                 SB + ((q * 256 + wv * 64) << 4));
    }
    __syncthreads();

    // ---- u GEMM: wave wv owns i-rows wv*16..+15; cols 0..127; K=128 ----
    f32x4 uacc[8] = {};
#pragma unroll
    for (int kk = 0; kk < 4; kk++) {
        int ch = kk * 4 + lg;
        int ra = wv * 16 + l15;
        bf16x8 a = *(const bf16x8*)(SA + ra * 256 + ((ch ^ (ra & 7)) << 4));
#pragma unroll
        for (int f = 0; f < 8; f++) {
            int rb = f * 16 + l15;
            bf16x8 bb = *(const bf16x8*)(SB + rb * 256 + ((ch ^ (rb & 7)) << 4));
            uacc[f] = __builtin_amdgcn_mfma_f32_16x16x32_bf16(a, bb, uacc[f], 0, 0, 0);
        }
    }
    // write u into SA (wave-local 16-row band; no barrier needed before writes)
#pragma unroll
    for (int f = 0; f < 8; f++)
#pragma unroll
        for (int r = 0; r < 4; r++) {
            int row = wv * 16 + lg * 4 + r;
            int col = f * 16 + l15;
            int cj = col >> 3;
            *(unsigned short*)(SA + row * 256 + ((cj ^ (row & 7)) << 4) + (col & 7) * 2)
                = f2bf(uacc[f][r]);
        }
    __syncthreads();   // all u written, all wsT reads done

    // ---- stage fzp chunk (16KB into SB) ----
#pragma unroll
    for (int q = 0; q < 4; q++) {
        int L = q * 256 + t, row = L >> 4, ch = (L & 15) ^ (row & 7);
        gl_lds16(P.fzp + (size_t)(jb + row) * Z + ch * 8,
                 SB + ((q * 256 + wv * 64) << 4));
    }
    __syncthreads();

    // ---- neg MFMAs: wave wv owns j-cols wv*16..+15; all 64 i-rows ----
    f32x4 a2[4] = {};
#pragma unroll
    for (int kk = 0; kk < 4; kk++) {
        int ch = kk * 4 + lg;
        bf16x8 a[4];
#pragma unroll
        for (int m = 0; m < 4; m++) {
            int ra = m * 16 + l15;
            a[m] = *(const bf16x8*)(SA + ra * 256 + ((ch ^ (ra & 7)) << 4));
        }
        int rb = wv * 16 + l15;
        bf16x8 bb = *(const bf16x8*)(SB + rb * 256 + ((ch ^ (rb & 7)) << 4));
#pragma unroll
        for (int m = 0; m < 4; m++)
            a2[m] = __builtin_amdgcn_mfma_f32_16x16x32_bf16(a[m], bb, a2[m], 0, 0, 0);
    }
    // T-diag: diagonal tile holds u[slot].fz[slot] in fp32
    if (jb == ibase) {
        int jl = wv * 16 + l15;
#pragma unroll
        for (int m = 0; m < 4; m++)
#pragma unroll
            for (int r = 0; r < 4; r++) {
                int il = m * 16 + lg * 4 + r;
                if (il == jl) P.Tv[ibase + il] = a2[m][r];
            }
    }
    bool jv = (jb + wv * 16 + l15) < jreal;
    float rsum[4][4];
#pragma unroll
    for (int m = 0; m < 4; m++)
#pragma unroll
        for (int r = 0; r < 4; r++)
            rsum[m][r] = jv ? softplus_f(a2[m][r]) : 0.f;
#pragma unroll
    for (int m = 0; m < 4; m++)
#pragma unroll
        for (int r = 0; r < 4; r++) {
            float v = rsum[m][r];
            v += __shfl_xor(v, 1, 16);
            v += __shfl_xor(v, 2, 16);
            v += __shfl_xor(v, 4, 16);
            v += __shfl_xor(v, 8, 16);
            if (l15 == 0) negw[wv][m * 16 + lg * 4 + r] = v;
        }
    __syncthreads();
    if (t < 64) {
        float ns = negw[0][t] + negw[1][t] + negw[2][t] + negw[3][t];
        P.negpart[(size_t)blockIdx.x * PADCAP + ibase + t] = ns;
    }
}

// ================= kernel 5: finalize (scalar per slot) =================
__global__ __launch_bounds__(256) void k_final(KParams P) {
    int slot = blockIdx.x * 256 + threadIdx.x;
    if (slot >= PADCAP) return;
    int pi = P.perm32[slot];
    if (pi < 0) return;
    float ns = 0.f;
#pragma unroll
    for (int q = 0; q < JY; q++) ns += P.negpart[(size_t)q * PADCAP + slot];
    int cat = P.tcat[slot >> 5];
    float T = softplus_f(P.Tv[slot]);
    float nT = ns / (float)P.cnt[cat];
    P.out[pi] = logf(T + EPS_F) - logf(nT + EPS_F);
}

extern "C" void kernel_launch(void* const* d_in, const int* in_sizes, int n_in,
                              void* d_out, int out_size, void* d_ws, size_t ws_size,
                              hipStream_t stream) {
    KParams P;
    P.x  = (const float*)d_in[0];
    P.c  = (const int*)d_in[1];
    P.z  = (const float*)d_in[2];
    P.W1 = (const float*)d_in[3];
    P.b1 = (const float*)d_in[4];
    P.W2 = (const float*)d_in[5];
    P.b2 = (const float*)d_in[6];
    P.Wz = (const float*)d_in[7];
    P.bz = (const float*)d_in[8];
    P.ws = (const float*)d_in[9];
    P.out = (float*)d_out;

    char* p = (char*)d_ws;
    P.Hp   = (unsigned short*)p; p += (size_t)PADCAP * HID * 2;
    P.fxp  = (unsigned short*)p; p += (size_t)PADCAP * Z * 2;
    P.fzp  = (unsigned short*)p; p += (size_t)PADCAP * Z * 2;
    P.W1t  = (unsigned short*)p; p += (size_t)D_IN * HID * 2;
    P.W2t  = (unsigned short*)p; p += (size_t)HID * Z * 2;
    P.Wzt  = (unsigned short*)p; p += (size_t)Z * Z * 2;
    P.wsT  = (unsigned short*)p; p += (size_t)NCAT * Z * Z * 2;
    P.Tv   = (float*)p;          p += (size_t)PADCAP * 4;
    P.negpart = (float*)p;       p += (size_t)JY * PADCAP * 4;
    P.perm32  = (int*)p;         p += (size_t)PADCAP * 4;
    P.inv     = (int*)p;         p += (size_t)N * 4;
    P.cnt     = (int*)p;         p += 256;
    P.offsP   = (int*)p;         p += 256;
    P.tcat    = (int*)p;         p += 2048;

    k_prep<<<dim3(465 + NZERO), dim3(256), 0, stream>>>(P);
    k_mid<<<dim3(640), dim3(256), 0, stream>>>(P);
    k_fx<<<dim3(2, PADCAP / 128), dim3(256), 0, stream>>>(P);
    k_negu<<<dim3(JY, T64CAP), dim3(256), 0, stream>>>(P);
    k_final<<<dim3((PADCAP + 255) / 256), dim3(256), 0, stream>>>(P);
}